// Round 1
// baseline (5179.336 us; speedup 1.0000x reference)
//
#include <hip/hip_runtime.h>

#define LRELU(x) ((x) > 0.0f ? (x) : 0.01f * (x))

__global__ void zero_kernel(float* p, int n) {
    int i = blockIdx.x * blockDim.x + threadIdx.x;
    if (i < n) p[i] = 0.0f;
}

// xact = act(in) (optional BN+leaky), agg = (1+eps)*xact
__global__ void init_kernel(const float4* __restrict__ xin,
                            const float* __restrict__ scale,
                            const float* __restrict__ shift,
                            const float* __restrict__ eps_gin, int layer,
                            float4* __restrict__ xact, float4* __restrict__ agg, int n4) {
    int i = blockIdx.x * blockDim.x + threadIdx.x;
    if (i >= n4) return;
    float4 v = xin[i];
    if (scale) {
        int d = (i & 15) * 4;
        v.x = LRELU(v.x * scale[d + 0] + shift[d + 0]);
        v.y = LRELU(v.y * scale[d + 1] + shift[d + 1]);
        v.z = LRELU(v.z * scale[d + 2] + shift[d + 2]);
        v.w = LRELU(v.w * scale[d + 3] + shift[d + 3]);
    }
    float ep = 1.0f + eps_gin[layer];
    xact[i] = v;
    agg[i] = make_float4(v.x * ep, v.y * ep, v.z * ep, v.w * ep);
}

// edge-parallel scatter-add: 16 lanes (float4 each) per edge
__global__ void scatter_kernel(const float4* __restrict__ xact, float* __restrict__ agg,
                               const int* __restrict__ src, const int* __restrict__ dst, int E) {
    int tid = blockIdx.x * blockDim.x + threadIdx.x;
    int e = tid >> 4;
    int q = tid & 15;
    if (e >= E) return;
    int s = src[e];
    int d = dst[e];
    float4 v = xact[s * 16 + q];
    float* base = agg + ((size_t)d * 64 + q * 4);
    atomicAdd(base + 0, v.x);
    atomicAdd(base + 1, v.y);
    atomicAdd(base + 2, v.z);
    atomicAdd(base + 3, v.w);
}

// per-column sum & sumsq over nrows; C in {64,128}; blockDim=256
__global__ void stats_kernel(const float* __restrict__ h, int nrows, int C,
                             float* __restrict__ sums) {
    __shared__ float red[512];
    int t = threadIdx.x;
    int d = t & (C - 1);
    int rb = t / C;
    int rpb = 256 / C;  // rows per iter per block
    float s = 0.0f, s2 = 0.0f;
    for (int row = blockIdx.x * rpb + rb; row < nrows; row += gridDim.x * rpb) {
        float v = h[(size_t)row * C + d];
        s += v;
        s2 += v * v;
    }
    red[t] = s;
    red[256 + t] = s2;
    __syncthreads();
    if (t < C) {
        for (int j = 1; j < rpb; j++) {
            s += red[t + j * C];
            s2 += red[256 + t + j * C];
        }
        atomicAdd(&sums[d], s);
        atomicAdd(&sums[C + d], s2);
    }
}

__global__ void finalize_kernel(const float* __restrict__ sums, const float* __restrict__ g,
                                const float* __restrict__ be, float* __restrict__ scale,
                                float* __restrict__ shift, int C, float invN) {
    int d = threadIdx.x;
    if (d >= C) return;
    float mean = sums[d] * invN;
    float var = sums[C + d] * invN - mean * mean;
    float sc = g[d] * rsqrtf(var + 1e-5f);
    scale[d] = sc;
    shift[d] = be[d] - mean * sc;
}

// out[nrows x COLS] = act(in[nrows x 64]) @ W[64 x COLS] + bias
// optional per-input-feature BN+leaky applied while staging input
template <int COLS>
__global__ __launch_bounds__(256) void gemm_kernel(const float* __restrict__ in,
                                                   const float* __restrict__ W,
                                                   const float* __restrict__ bias,
                                                   const float* __restrict__ scale,
                                                   const float* __restrict__ shift,
                                                   float* __restrict__ out, int nrows) {
    __shared__ float inT[64][68];   // [k][row], padded for 16B-aligned rows
    __shared__ float ws[64][COLS];  // [k][col]
    int t = threadIdx.x;
    int row0 = blockIdx.x * 64;

    // stage input transposed; rows beyond nrows -> 0 (never stored)
    for (int i = 0; i < 4; i++) {
        int f = t + 256 * i;
        int r = f & 63;
        int c4 = f >> 6;
        int gr = row0 + r;
        float4 v = make_float4(0.f, 0.f, 0.f, 0.f);
        if (gr < nrows) v = *(const float4*)&in[(size_t)gr * 64 + c4 * 4];
        if (scale) {
            int d = c4 * 4;
            v.x = LRELU(v.x * scale[d + 0] + shift[d + 0]);
            v.y = LRELU(v.y * scale[d + 1] + shift[d + 1]);
            v.z = LRELU(v.z * scale[d + 2] + shift[d + 2]);
            v.w = LRELU(v.w * scale[d + 3] + shift[d + 3]);
        }
        inT[c4 * 4 + 0][r] = v.x;
        inT[c4 * 4 + 1][r] = v.y;
        inT[c4 * 4 + 2][r] = v.z;
        inT[c4 * 4 + 3][r] = v.w;
    }
    // stage W
    for (int i = 0; i < COLS / 16; i++) {
        int f = t + 256 * i;
        int k = f / (COLS / 4);
        int c4 = f % (COLS / 4);
        *(float4*)&ws[k][c4 * 4] = *(const float4*)&W[(size_t)k * COLS + c4 * 4];
    }
    __syncthreads();

    constexpr int CPT = COLS / 16;  // 4 or 8 cols per thread
    int rg = t >> 4;
    int cg = t & 15;
    int r0 = rg * 4;
    int c0 = cg * CPT;
    float acc[4][CPT];
#pragma unroll
    for (int r = 0; r < 4; r++)
#pragma unroll
        for (int c = 0; c < CPT; c++) acc[r][c] = 0.0f;

#pragma unroll
    for (int k = 0; k < 64; k++) {
        float4 a = *(const float4*)&inT[k][r0];
        float ar[4] = {a.x, a.y, a.z, a.w};
#pragma unroll
        for (int jj = 0; jj < CPT / 4; jj++) {
            float4 w4 = *(const float4*)&ws[k][c0 + jj * 4];
            float wr[4] = {w4.x, w4.y, w4.z, w4.w};
#pragma unroll
            for (int r = 0; r < 4; r++)
#pragma unroll
                for (int c = 0; c < 4; c++) acc[r][jj * 4 + c] += ar[r] * wr[c];
        }
    }

#pragma unroll
    for (int r = 0; r < 4; r++) {
        int gr = row0 + r0 + r;
        if (gr < nrows) {
#pragma unroll
            for (int jj = 0; jj < CPT / 4; jj++) {
                float4 bv = *(const float4*)&bias[c0 + jj * 4];
                float4 o = make_float4(acc[r][jj * 4 + 0] + bv.x, acc[r][jj * 4 + 1] + bv.y,
                                       acc[r][jj * 4 + 2] + bv.z, acc[r][jj * 4 + 3] + bv.w);
                *(float4*)&out[(size_t)gr * COLS + c0 + jj * 4] = o;
            }
        }
    }
}

// out[row] = (lrelu(bn(hf[row,:]))) . Wf2 + bf2 ; one wave per row
__global__ void head_out_kernel(const float* __restrict__ hf, const float* __restrict__ scale,
                                const float* __restrict__ shift, const float* __restrict__ Wf2,
                                const float* __restrict__ bf2, float* __restrict__ out,
                                int nrows) {
    int gtid = blockIdx.x * blockDim.x + threadIdx.x;
    int wid = gtid >> 6;
    int l = threadIdx.x & 63;
    if (wid >= nrows) return;
    float v0 = hf[(size_t)wid * 128 + l];
    float v1 = hf[(size_t)wid * 128 + 64 + l];
    v0 = LRELU(v0 * scale[l] + shift[l]);
    v1 = LRELU(v1 * scale[64 + l] + shift[64 + l]);
    float p = v0 * Wf2[l] + v1 * Wf2[64 + l];
    for (int o = 32; o > 0; o >>= 1) p += __shfl_down(p, o);
    if (l == 0) out[wid] = p + bf2[0];
}

extern "C" void kernel_launch(void* const* d_in, const int* in_sizes, int n_in, void* d_out,
                              int out_size, void* d_ws, size_t ws_size, hipStream_t stream) {
    const float* x = (const float*)d_in[0];
    const int* esrc = (const int*)d_in[1];
    const int* edst = (const int*)d_in[2];
    const float* W1 = (const float*)d_in[3];
    const float* b1 = (const float*)d_in[4];
    const float* g1 = (const float*)d_in[5];
    const float* be1 = (const float*)d_in[6];
    const float* W2 = (const float*)d_in[7];
    const float* b2 = (const float*)d_in[8];
    const float* eps_gin = (const float*)d_in[9];
    const float* g_bn = (const float*)d_in[10];
    const float* b_bn = (const float*)d_in[11];
    const float* Wf1 = (const float*)d_in[12];
    const float* bf1 = (const float*)d_in[13];
    const float* gf = (const float*)d_in[14];
    const float* bef = (const float*)d_in[15];
    const float* Wf2 = (const float*)d_in[16];
    const float* bf2 = (const float*)d_in[17];
    float* out = (float*)d_out;

    int N = in_sizes[0] / 64;
    int E = in_sizes[1];
    float invN = 1.0f / (float)N;

    float* ws = (float*)d_ws;
    size_t ND = (size_t)N * 64;
    float* X = ws;            // current layer output (raw, pre outer-BN)
    float* S1 = ws + ND;      // xact, then h1 (aliased)
    float* S2 = ws + 2 * ND;  // agg
    float* HF = S1;           // head hidden (N x 128) spans S1+S2
    float* stats = ws + 3 * ND;
    // stats set s: [sums 2C][..][scale @+256][shift @+384], 512 floats each
    // s0: L0 inner, s1: L0 outer, s2: L1 inner, s3: L1 outer, s4: L2 inner, s5: head

    zero_kernel<<<(3072 + 255) / 256, 256, 0, stream>>>(stats, 3072);

    int n4 = N * 16;
    for (int i = 0; i < 3; i++) {
        const float4* xin = (i == 0) ? (const float4*)x : (const float4*)X;
        const float* sc = nullptr;
        const float* sh = nullptr;
        if (i > 0) {
            float* so = stats + (size_t)(2 * (i - 1) + 1) * 512;
            sc = so + 256;
            sh = so + 384;
        }
        init_kernel<<<(n4 + 255) / 256, 256, 0, stream>>>(xin, sc, sh, eps_gin, i, (float4*)S1,
                                                          (float4*)S2, n4);
        scatter_kernel<<<(E * 16 + 255) / 256, 256, 0, stream>>>((const float4*)S1, S2, esrc,
                                                                 edst, E);
        gemm_kernel<64><<<(N + 63) / 64, 256, 0, stream>>>(S2, W1 + (size_t)i * 4096,
                                                           b1 + (size_t)i * 64, nullptr, nullptr,
                                                           S1, N);
        float* st = stats + (size_t)(2 * i) * 512;
        stats_kernel<<<256, 256, 0, stream>>>(S1, N, 64, st);
        finalize_kernel<<<1, 64, 0, stream>>>(st, g1 + (size_t)i * 64, be1 + (size_t)i * 64,
                                              st + 256, st + 384, 64, invN);
        gemm_kernel<64><<<(N + 63) / 64, 256, 0, stream>>>(S1, W2 + (size_t)i * 4096,
                                                           b2 + (size_t)i * 64, st + 256,
                                                           st + 384, X, N);
        if (i < 2) {
            float* so = stats + (size_t)(2 * i + 1) * 512;
            stats_kernel<<<256, 256, 0, stream>>>(X, N, 64, so);
            finalize_kernel<<<1, 64, 0, stream>>>(so, g_bn + (size_t)i * 64,
                                                  b_bn + (size_t)i * 64, so + 256, so + 384, 64,
                                                  invN);
        }
    }

    // head
    gemm_kernel<128><<<(N + 63) / 64, 256, 0, stream>>>(X, Wf1, bf1, nullptr, nullptr, HF, N);
    float* sf = stats + (size_t)5 * 512;
    stats_kernel<<<256, 256, 0, stream>>>(HF, N, 128, sf);
    finalize_kernel<<<1, 128, 0, stream>>>(sf, gf, bef, sf + 256, sf + 384, 128, invN);
    head_out_kernel<<<(N + 3) / 4, 256, 0, stream>>>(HF, sf + 256, sf + 384, Wf2, bf2, out, N);
}

// Round 2
// 1495.109 us; speedup vs baseline: 3.4642x; 3.4642x over previous
//
#include <hip/hip_runtime.h>

#define LRELU(x) ((x) > 0.0f ? (x) : 0.01f * (x))

__global__ void zero_kernel(float* p, int n) {
    int i = blockIdx.x * blockDim.x + threadIdx.x;
    if (i < n) p[i] = 0.0f;
}

// xact = LRELU(BN(xin)) -- used for layers 1,2 (layer 0 reads x directly)
__global__ void act_kernel(const float4* __restrict__ xin, const float* __restrict__ scale,
                           const float* __restrict__ shift, float4* __restrict__ xact, int n4) {
    int i = blockIdx.x * blockDim.x + threadIdx.x;
    if (i >= n4) return;
    float4 v = xin[i];
    int d = (i & 15) * 4;
    v.x = LRELU(v.x * scale[d + 0] + shift[d + 0]);
    v.y = LRELU(v.y * scale[d + 1] + shift[d + 1]);
    v.z = LRELU(v.z * scale[d + 2] + shift[d + 2]);
    v.w = LRELU(v.w * scale[d + 3] + shift[d + 3]);
    xact[i] = v;
}

// ---------- CSR build ----------
__global__ void hist_kernel(const int* __restrict__ dst, int* __restrict__ cnt, int E) {
    int e = blockIdx.x * blockDim.x + threadIdx.x;
    if (e < E) atomicAdd(&cnt[dst[e]], 1);
}

// per-block (1024 elems) exclusive scan; blksum[b] = block total
__global__ __launch_bounds__(256) void scan1_kernel(const int* __restrict__ cnt,
                                                    int* __restrict__ ptr,
                                                    int* __restrict__ blksum, int n) {
    __shared__ int sh[256];
    int t = threadIdx.x;
    int base = blockIdx.x * 1024 + t * 4;
    int c0 = (base + 0 < n) ? cnt[base + 0] : 0;
    int c1 = (base + 1 < n) ? cnt[base + 1] : 0;
    int c2 = (base + 2 < n) ? cnt[base + 2] : 0;
    int c3 = (base + 3 < n) ? cnt[base + 3] : 0;
    int tsum = c0 + c1 + c2 + c3;
    sh[t] = tsum;
    __syncthreads();
    for (int o = 1; o < 256; o <<= 1) {
        int v = (t >= o) ? sh[t - o] : 0;
        __syncthreads();
        sh[t] += v;
        __syncthreads();
    }
    int excl = sh[t] - tsum;  // block-exclusive prefix for this thread
    if (base + 0 < n) ptr[base + 0] = excl;
    excl += c0;
    if (base + 1 < n) ptr[base + 1] = excl;
    excl += c1;
    if (base + 2 < n) ptr[base + 2] = excl;
    excl += c2;
    if (base + 3 < n) ptr[base + 3] = excl;
    if (t == 255) blksum[blockIdx.x] = sh[255];
}

// single-block exclusive scan of blksum (nb <= 256)
__global__ __launch_bounds__(256) void scan2_kernel(int* __restrict__ blksum, int nb) {
    __shared__ int sh[256];
    int t = threadIdx.x;
    int v0 = (t < nb) ? blksum[t] : 0;
    sh[t] = v0;
    __syncthreads();
    for (int o = 1; o < 256; o <<= 1) {
        int v = (t >= o) ? sh[t - o] : 0;
        __syncthreads();
        sh[t] += v;
        __syncthreads();
    }
    if (t < nb) blksum[t] = sh[t] - v0;
}

__global__ void scan3_kernel(int* __restrict__ ptr, const int* __restrict__ blksum,
                             int* __restrict__ cursor, int n) {
    int i = blockIdx.x * blockDim.x + threadIdx.x;
    if (i >= n) return;
    int p = ptr[i] + blksum[i >> 10];
    ptr[i] = p;
    cursor[i] = p;
}

__global__ void fill_kernel(const int* __restrict__ src, const int* __restrict__ dst,
                            int* __restrict__ cursor, int* __restrict__ nbr, int E) {
    int e = blockIdx.x * blockDim.x + threadIdx.x;
    if (e >= E) return;
    int d = dst[e];
    int pos = atomicAdd(&cursor[d], 1);
    nbr[pos] = src[e];
}

// ---------- aggregation: one 64-lane wave per node ----------
__global__ __launch_bounds__(256) void gather_kernel(const float* __restrict__ xact,
                                                     const int* __restrict__ ptr,
                                                     const int* __restrict__ cnt,
                                                     const int* __restrict__ nbr,
                                                     const float* __restrict__ eps_gin, int layer,
                                                     float* __restrict__ agg, int N) {
    int gtid = blockIdx.x * blockDim.x + threadIdx.x;
    int node = gtid >> 6;
    int lane = threadIdx.x & 63;
    if (node >= N) return;
    int start = ptr[node];
    int deg = cnt[node];
    float s = 0.0f;
    int j = 0;
    for (; j + 4 <= deg; j += 4) {
        int n0 = nbr[start + j + 0];
        int n1 = nbr[start + j + 1];
        int n2 = nbr[start + j + 2];
        int n3 = nbr[start + j + 3];
        float v0 = xact[(size_t)n0 * 64 + lane];
        float v1 = xact[(size_t)n1 * 64 + lane];
        float v2 = xact[(size_t)n2 * 64 + lane];
        float v3 = xact[(size_t)n3 * 64 + lane];
        s += (v0 + v1) + (v2 + v3);
    }
    for (; j < deg; j++) s += xact[(size_t)nbr[start + j] * 64 + lane];
    float ep = 1.0f + eps_gin[layer];
    agg[(size_t)node * 64 + lane] = s + ep * xact[(size_t)node * 64 + lane];
}

// per-column sum & sumsq over nrows; C in {64,128}; blockDim=256
__global__ void stats_kernel(const float* __restrict__ h, int nrows, int C,
                             float* __restrict__ sums) {
    __shared__ float red[512];
    int t = threadIdx.x;
    int d = t & (C - 1);
    int rb = t / C;
    int rpb = 256 / C;
    float s = 0.0f, s2 = 0.0f;
    for (int row = blockIdx.x * rpb + rb; row < nrows; row += gridDim.x * rpb) {
        float v = h[(size_t)row * C + d];
        s += v;
        s2 += v * v;
    }
    red[t] = s;
    red[256 + t] = s2;
    __syncthreads();
    if (t < C) {
        for (int j = 1; j < rpb; j++) {
            s += red[t + j * C];
            s2 += red[256 + t + j * C];
        }
        atomicAdd(&sums[d], s);
        atomicAdd(&sums[C + d], s2);
    }
}

__global__ void finalize_kernel(const float* __restrict__ sums, const float* __restrict__ g,
                                const float* __restrict__ be, float* __restrict__ scale,
                                float* __restrict__ shift, int C, float invN) {
    int d = threadIdx.x;
    if (d >= C) return;
    float mean = sums[d] * invN;
    float var = sums[C + d] * invN - mean * mean;
    float sc = g[d] * rsqrtf(var + 1e-5f);
    scale[d] = sc;
    shift[d] = be[d] - mean * sc;
}

// out[nrows x COLS] = act(in[nrows x 64]) @ W[64 x COLS] + bias
template <int COLS>
__global__ __launch_bounds__(256) void gemm_kernel(const float* __restrict__ in,
                                                   const float* __restrict__ W,
                                                   const float* __restrict__ bias,
                                                   const float* __restrict__ scale,
                                                   const float* __restrict__ shift,
                                                   float* __restrict__ out, int nrows) {
    __shared__ float inT[64][68];
    __shared__ float ws[64][COLS];
    int t = threadIdx.x;
    int row0 = blockIdx.x * 64;

    for (int i = 0; i < 4; i++) {
        int f = t + 256 * i;
        int r = f & 63;
        int c4 = f >> 6;
        int gr = row0 + r;
        float4 v = make_float4(0.f, 0.f, 0.f, 0.f);
        if (gr < nrows) v = *(const float4*)&in[(size_t)gr * 64 + c4 * 4];
        if (scale) {
            int d = c4 * 4;
            v.x = LRELU(v.x * scale[d + 0] + shift[d + 0]);
            v.y = LRELU(v.y * scale[d + 1] + shift[d + 1]);
            v.z = LRELU(v.z * scale[d + 2] + shift[d + 2]);
            v.w = LRELU(v.w * scale[d + 3] + shift[d + 3]);
        }
        inT[c4 * 4 + 0][r] = v.x;
        inT[c4 * 4 + 1][r] = v.y;
        inT[c4 * 4 + 2][r] = v.z;
        inT[c4 * 4 + 3][r] = v.w;
    }
    for (int i = 0; i < COLS / 16; i++) {
        int f = t + 256 * i;
        int k = f / (COLS / 4);
        int c4 = f % (COLS / 4);
        *(float4*)&ws[k][c4 * 4] = *(const float4*)&W[(size_t)k * COLS + c4 * 4];
    }
    __syncthreads();

    constexpr int CPT = COLS / 16;
    int rg = t >> 4;
    int cg = t & 15;
    int r0 = rg * 4;
    int c0 = cg * CPT;
    float acc[4][CPT];
#pragma unroll
    for (int r = 0; r < 4; r++)
#pragma unroll
        for (int c = 0; c < CPT; c++) acc[r][c] = 0.0f;

#pragma unroll
    for (int k = 0; k < 64; k++) {
        float4 a = *(const float4*)&inT[k][r0];
        float ar[4] = {a.x, a.y, a.z, a.w};
#pragma unroll
        for (int jj = 0; jj < CPT / 4; jj++) {
            float4 w4 = *(const float4*)&ws[k][c0 + jj * 4];
            float wr[4] = {w4.x, w4.y, w4.z, w4.w};
#pragma unroll
            for (int r = 0; r < 4; r++)
#pragma unroll
                for (int c = 0; c < 4; c++) acc[r][jj * 4 + c] += ar[r] * wr[c];
        }
    }

#pragma unroll
    for (int r = 0; r < 4; r++) {
        int gr = row0 + r0 + r;
        if (gr < nrows) {
#pragma unroll
            for (int jj = 0; jj < CPT / 4; jj++) {
                float4 bv = *(const float4*)&bias[c0 + jj * 4];
                float4 o = make_float4(acc[r][jj * 4 + 0] + bv.x, acc[r][jj * 4 + 1] + bv.y,
                                       acc[r][jj * 4 + 2] + bv.z, acc[r][jj * 4 + 3] + bv.w);
                *(float4*)&out[(size_t)gr * COLS + c0 + jj * 4] = o;
            }
        }
    }
}

__global__ void head_out_kernel(const float* __restrict__ hf, const float* __restrict__ scale,
                                const float* __restrict__ shift, const float* __restrict__ Wf2,
                                const float* __restrict__ bf2, float* __restrict__ out,
                                int nrows) {
    int gtid = blockIdx.x * blockDim.x + threadIdx.x;
    int wid = gtid >> 6;
    int l = threadIdx.x & 63;
    if (wid >= nrows) return;
    float v0 = hf[(size_t)wid * 128 + l];
    float v1 = hf[(size_t)wid * 128 + 64 + l];
    v0 = LRELU(v0 * scale[l] + shift[l]);
    v1 = LRELU(v1 * scale[64 + l] + shift[64 + l]);
    float p = v0 * Wf2[l] + v1 * Wf2[64 + l];
    for (int o = 32; o > 0; o >>= 1) p += __shfl_down(p, o);
    if (l == 0) out[wid] = p + bf2[0];
}

extern "C" void kernel_launch(void* const* d_in, const int* in_sizes, int n_in, void* d_out,
                              int out_size, void* d_ws, size_t ws_size, hipStream_t stream) {
    const float* x = (const float*)d_in[0];
    const int* esrc = (const int*)d_in[1];
    const int* edst = (const int*)d_in[2];
    const float* W1 = (const float*)d_in[3];
    const float* b1 = (const float*)d_in[4];
    const float* g1 = (const float*)d_in[5];
    const float* be1 = (const float*)d_in[6];
    const float* W2 = (const float*)d_in[7];
    const float* b2 = (const float*)d_in[8];
    const float* eps_gin = (const float*)d_in[9];
    const float* g_bn = (const float*)d_in[10];
    const float* b_bn = (const float*)d_in[11];
    const float* Wf1 = (const float*)d_in[12];
    const float* bf1 = (const float*)d_in[13];
    const float* gf = (const float*)d_in[14];
    const float* bef = (const float*)d_in[15];
    const float* Wf2 = (const float*)d_in[16];
    const float* bf2 = (const float*)d_in[17];
    float* out = (float*)d_out;

    int N = in_sizes[0] / 64;
    int E = in_sizes[1];
    float invN = 1.0f / (float)N;

    float* ws = (float*)d_ws;
    size_t ND = (size_t)N * 64;
    float* X = ws;            // raw layer output (pre outer-BN)
    float* S1 = ws + ND;      // xact, then h1 (aliased)
    float* S2 = ws + 2 * ND;  // agg
    float* HF = S1;           // head hidden (N x 128) spans S1+S2
    float* stats = ws + 3 * ND;
    // CSR arrays after stats (ints)
    int* ibase = (int*)(stats + 3072);
    int* cnt = ibase;
    int* ptr = ibase + N;
    int* cursor = ibase + 2 * N;
    int* blksum = ibase + 3 * N;
    int* nbr = ibase + 3 * N + 256;

    // zero stats (3072 floats) + cnt (N ints, contiguous after stats)
    zero_kernel<<<(3072 + N + 255) / 256, 256, 0, stream>>>(stats, 3072 + N);

    // ---- CSR build (once; reused by all 3 layers) ----
    int nb1 = (N + 1023) / 1024;
    hist_kernel<<<(E + 255) / 256, 256, 0, stream>>>(edst, cnt, E);
    scan1_kernel<<<nb1, 256, 0, stream>>>(cnt, ptr, blksum, N);
    scan2_kernel<<<1, 256, 0, stream>>>(blksum, nb1);
    scan3_kernel<<<(N + 255) / 256, 256, 0, stream>>>(ptr, blksum, cursor, N);
    fill_kernel<<<(E + 255) / 256, 256, 0, stream>>>(esrc, edst, cursor, nbr, E);

    int n4 = N * 16;
    int gblocks = (N * 64 + 255) / 256;
    for (int i = 0; i < 3; i++) {
        const float* xact;
        if (i == 0) {
            xact = x;
        } else {
            float* so = stats + (size_t)(2 * (i - 1) + 1) * 512;
            act_kernel<<<(n4 + 255) / 256, 256, 0, stream>>>((const float4*)X, so + 256,
                                                             so + 384, (float4*)S1, n4);
            xact = S1;
        }
        gather_kernel<<<gblocks, 256, 0, stream>>>(xact, ptr, cnt, nbr, eps_gin, i, S2, N);
        gemm_kernel<64><<<(N + 63) / 64, 256, 0, stream>>>(S2, W1 + (size_t)i * 4096,
                                                           b1 + (size_t)i * 64, nullptr, nullptr,
                                                           S1, N);
        float* st = stats + (size_t)(2 * i) * 512;
        stats_kernel<<<256, 256, 0, stream>>>(S1, N, 64, st);
        finalize_kernel<<<1, 64, 0, stream>>>(st, g1 + (size_t)i * 64, be1 + (size_t)i * 64,
                                              st + 256, st + 384, 64, invN);
        gemm_kernel<64><<<(N + 63) / 64, 256, 0, stream>>>(S1, W2 + (size_t)i * 4096,
                                                           b2 + (size_t)i * 64, st + 256,
                                                           st + 384, X, N);
        if (i < 2) {
            float* so = stats + (size_t)(2 * i + 1) * 512;
            stats_kernel<<<256, 256, 0, stream>>>(X, N, 64, so);
            finalize_kernel<<<1, 64, 0, stream>>>(so, g_bn + (size_t)i * 64,
                                                  b_bn + (size_t)i * 64, so + 256, so + 384, 64,
                                                  invN);
        }
    }

    gemm_kernel<128><<<(N + 63) / 64, 256, 0, stream>>>(X, Wf1, bf1, nullptr, nullptr, HF, N);
    float* sf = stats + (size_t)5 * 512;
    stats_kernel<<<256, 256, 0, stream>>>(HF, N, 128, sf);
    finalize_kernel<<<1, 128, 0, stream>>>(sf, gf, bef, sf + 256, sf + 384, 128, invN);
    head_out_kernel<<<(N + 3) / 4, 256, 0, stream>>>(HF, sf + 256, sf + 384, Wf2, bf2, out, N);
}

// Round 4
// 1481.161 us; speedup vs baseline: 3.4968x; 1.0094x over previous
//
#include <hip/hip_runtime.h>

#define LRELU(x) ((x) > 0.0f ? (x) : 0.01f * (x))

__global__ void zero_kernel(float* p, int n) {
    int i = blockIdx.x * blockDim.x + threadIdx.x;
    if (i < n) p[i] = 0.0f;
}

// ---------- CSR build ----------
__global__ void hist_kernel(const int* __restrict__ dst, int* __restrict__ cnt, int E) {
    int e = blockIdx.x * blockDim.x + threadIdx.x;
    if (e < E) atomicAdd(&cnt[dst[e]], 1);
}

__global__ __launch_bounds__(256) void scan1_kernel(const int* __restrict__ cnt,
                                                    int* __restrict__ ptr,
                                                    int* __restrict__ blksum, int n) {
    __shared__ int sh[256];
    int t = threadIdx.x;
    int base = blockIdx.x * 1024 + t * 4;
    int c0 = (base + 0 < n) ? cnt[base + 0] : 0;
    int c1 = (base + 1 < n) ? cnt[base + 1] : 0;
    int c2 = (base + 2 < n) ? cnt[base + 2] : 0;
    int c3 = (base + 3 < n) ? cnt[base + 3] : 0;
    int tsum = c0 + c1 + c2 + c3;
    sh[t] = tsum;
    __syncthreads();
    for (int o = 1; o < 256; o <<= 1) {
        int v = (t >= o) ? sh[t - o] : 0;
        __syncthreads();
        sh[t] += v;
        __syncthreads();
    }
    int excl = sh[t] - tsum;
    if (base + 0 < n) ptr[base + 0] = excl;
    excl += c0;
    if (base + 1 < n) ptr[base + 1] = excl;
    excl += c1;
    if (base + 2 < n) ptr[base + 2] = excl;
    excl += c2;
    if (base + 3 < n) ptr[base + 3] = excl;
    if (t == 255) blksum[blockIdx.x] = sh[255];
}

__global__ __launch_bounds__(256) void scan2_kernel(int* __restrict__ blksum, int nb) {
    __shared__ int sh[256];
    int t = threadIdx.x;
    int v0 = (t < nb) ? blksum[t] : 0;
    sh[t] = v0;
    __syncthreads();
    for (int o = 1; o < 256; o <<= 1) {
        int v = (t >= o) ? sh[t - o] : 0;
        __syncthreads();
        sh[t] += v;
        __syncthreads();
    }
    if (t < nb) blksum[t] = sh[t] - v0;
}

__global__ void scan3_kernel(int* __restrict__ ptr, const int* __restrict__ blksum,
                             int* __restrict__ cursor, int n) {
    int i = blockIdx.x * blockDim.x + threadIdx.x;
    if (i >= n) return;
    int p = ptr[i] + blksum[i >> 10];
    ptr[i] = p;
    cursor[i] = p;
}

__global__ void fill_kernel(const int* __restrict__ src, const int* __restrict__ dst,
                            int* __restrict__ cursor, int* __restrict__ nbr, int E) {
    int e = blockIdx.x * blockDim.x + threadIdx.x;
    if (e >= E) return;
    int d = dst[e];
    int pos = atomicAdd(&cursor[d], 1);
    nbr[pos] = src[e];
}

// ---------- aggregation: one 64-lane wave per node, activation fused ----------
template <bool ACT>
__global__ __launch_bounds__(256) void gather_kernel(const float* __restrict__ xin,
                                                     const int* __restrict__ ptr,
                                                     const int* __restrict__ cnt,
                                                     const int* __restrict__ nbr,
                                                     const float* __restrict__ eps_gin, int layer,
                                                     const float* __restrict__ scale,
                                                     const float* __restrict__ shift,
                                                     float* __restrict__ agg, int N) {
    int gtid = blockIdx.x * blockDim.x + threadIdx.x;
    int node = gtid >> 6;
    int lane = threadIdx.x & 63;
    if (node >= N) return;
    float sc = ACT ? scale[lane] : 1.0f;
    float sh = ACT ? shift[lane] : 0.0f;
    int start = ptr[node];
    int deg = cnt[node];
    float s = 0.0f;
    int j = 0;
    for (; j + 4 <= deg; j += 4) {
        int n0 = nbr[start + j + 0];
        int n1 = nbr[start + j + 1];
        int n2 = nbr[start + j + 2];
        int n3 = nbr[start + j + 3];
        float v0 = xin[(size_t)n0 * 64 + lane];
        float v1 = xin[(size_t)n1 * 64 + lane];
        float v2 = xin[(size_t)n2 * 64 + lane];
        float v3 = xin[(size_t)n3 * 64 + lane];
        if (ACT) {
            v0 = LRELU(v0 * sc + sh);
            v1 = LRELU(v1 * sc + sh);
            v2 = LRELU(v2 * sc + sh);
            v3 = LRELU(v3 * sc + sh);
        }
        s += (v0 + v1) + (v2 + v3);
    }
    for (; j < deg; j++) {
        float v = xin[(size_t)nbr[start + j] * 64 + lane];
        if (ACT) v = LRELU(v * sc + sh);
        s += v;
    }
    float self = xin[(size_t)node * 64 + lane];
    if (ACT) self = LRELU(self * sc + sh);
    float ep = 1.0f + eps_gin[layer];
    agg[(size_t)node * 64 + lane] = s + ep * self;
}

__global__ void finalize_kernel(const float* __restrict__ sums, const float* __restrict__ g,
                                const float* __restrict__ be, float* __restrict__ scale,
                                float* __restrict__ shift, int C, float invN) {
    int d = threadIdx.x;
    if (d >= C) return;
    float mean = sums[d] * invN;
    float var = sums[C + d] * invN - mean * mean;
    float sc = g[d] * rsqrtf(var + 1e-5f);
    scale[d] = sc;
    shift[d] = be[d] - mean * sc;
}

// out[nrows x COLS] = act(in[nrows x 64]) @ W[64 x COLS] + bias
// optional fused col-stats (sums != nullptr)
template <int COLS>
__global__ __launch_bounds__(256) void gemm_kernel(const float* __restrict__ in,
                                                   const float* __restrict__ W,
                                                   const float* __restrict__ bias,
                                                   const float* __restrict__ scale,
                                                   const float* __restrict__ shift,
                                                   float* __restrict__ out,
                                                   float* __restrict__ sums, int nrows) {
    __shared__ float inT[64][68];   // [k][row], rows 16B-aligned
    __shared__ float ws[64][COLS];  // [k][col]
    int t = threadIdx.x;
    int row0 = blockIdx.x * 64;

    // coalesced staging: f -> (row = f>>4, chunk = f&15); transposed LDS write
    for (int i = 0; i < 4; i++) {
        int f = t + 256 * i;
        int r = f >> 4;
        int ch = f & 15;
        int gr = row0 + r;
        float4 v = make_float4(0.f, 0.f, 0.f, 0.f);
        if (gr < nrows) v = *(const float4*)&in[(size_t)gr * 64 + ch * 4];
        if (scale) {
            int d = ch * 4;
            v.x = LRELU(v.x * scale[d + 0] + shift[d + 0]);
            v.y = LRELU(v.y * scale[d + 1] + shift[d + 1]);
            v.z = LRELU(v.z * scale[d + 2] + shift[d + 2]);
            v.w = LRELU(v.w * scale[d + 3] + shift[d + 3]);
        }
        inT[ch * 4 + 0][r] = v.x;
        inT[ch * 4 + 1][r] = v.y;
        inT[ch * 4 + 2][r] = v.z;
        inT[ch * 4 + 3][r] = v.w;
    }
    for (int i = 0; i < COLS / 16; i++) {
        int f = t + 256 * i;
        int k = f / (COLS / 4);
        int c4 = f % (COLS / 4);
        *(float4*)&ws[k][c4 * 4] = *(const float4*)&W[(size_t)k * COLS + c4 * 4];
    }
    __syncthreads();

    constexpr int NCH = COLS / 64;  // 1 or 2 column chunks of 4 per thread
    int rg = t >> 4;
    int cg = t & 15;
    int r0 = rg * 4;
    int c0 = cg * 4;  // chunk jj covers cols c0 + jj*64 .. +3  (2-way LDS = free)
    float acc[4][NCH * 4];
#pragma unroll
    for (int r = 0; r < 4; r++)
#pragma unroll
        for (int c = 0; c < NCH * 4; c++) acc[r][c] = 0.0f;

#pragma unroll
    for (int k = 0; k < 64; k++) {
        float4 a = *(const float4*)&inT[k][r0];
        float ar[4] = {a.x, a.y, a.z, a.w};
#pragma unroll
        for (int jj = 0; jj < NCH; jj++) {
            float4 w4 = *(const float4*)&ws[k][c0 + jj * 64];
            float wr[4] = {w4.x, w4.y, w4.z, w4.w};
#pragma unroll
            for (int r = 0; r < 4; r++)
#pragma unroll
                for (int c = 0; c < 4; c++) acc[r][jj * 4 + c] += ar[r] * wr[c];
        }
    }

    // epilogue: bias, store (coalesced), per-thread col partial stats
    float ps[NCH * 4], ps2[NCH * 4];
#pragma unroll
    for (int c = 0; c < NCH * 4; c++) ps[c] = ps2[c] = 0.0f;
#pragma unroll
    for (int r = 0; r < 4; r++) {
        int gr = row0 + r0 + r;
        if (gr < nrows) {
#pragma unroll
            for (int jj = 0; jj < NCH; jj++) {
                float4 bv = *(const float4*)&bias[c0 + jj * 64];
                float4 o = make_float4(acc[r][jj * 4 + 0] + bv.x, acc[r][jj * 4 + 1] + bv.y,
                                       acc[r][jj * 4 + 2] + bv.z, acc[r][jj * 4 + 3] + bv.w);
                *(float4*)&out[(size_t)gr * COLS + c0 + jj * 64] = o;
                ps[jj * 4 + 0] += o.x;
                ps2[jj * 4 + 0] += o.x * o.x;
                ps[jj * 4 + 1] += o.y;
                ps2[jj * 4 + 1] += o.y * o.y;
                ps[jj * 4 + 2] += o.z;
                ps2[jj * 4 + 2] += o.z * o.z;
                ps[jj * 4 + 3] += o.w;
                ps2[jj * 4 + 3] += o.w * o.w;
            }
        }
    }

    if (sums == nullptr) return;  // no BN stats needed (layer L-1 outer output)

    // block reduce stats (reuse inT as scratch: 2*16*COLS floats <= 16KB)
    __syncthreads();
    float* red = &inT[0][0];
    float* red2 = red + 16 * COLS;
#pragma unroll
    for (int jj = 0; jj < NCH; jj++) {
        *(float4*)&red[rg * COLS + c0 + jj * 64] = *(float4*)&ps[jj * 4];
        *(float4*)&red2[rg * COLS + c0 + jj * 64] = *(float4*)&ps2[jj * 4];
    }
    __syncthreads();
    if (t < COLS) {
        float s = 0.0f, s2 = 0.0f;
#pragma unroll
        for (int j = 0; j < 16; j++) {
            s += red[j * COLS + t];
            s2 += red2[j * COLS + t];
        }
        atomicAdd(&sums[t], s);
        atomicAdd(&sums[COLS + t], s2);
    }
}

__global__ void head_out_kernel(const float* __restrict__ hf, const float* __restrict__ scale,
                                const float* __restrict__ shift, const float* __restrict__ Wf2,
                                const float* __restrict__ bf2, float* __restrict__ out,
                                int nrows) {
    int gtid = blockIdx.x * blockDim.x + threadIdx.x;
    int wid = gtid >> 6;
    int l = threadIdx.x & 63;
    if (wid >= nrows) return;
    float v0 = hf[(size_t)wid * 128 + l];
    float v1 = hf[(size_t)wid * 128 + 64 + l];
    v0 = LRELU(v0 * scale[l] + shift[l]);
    v1 = LRELU(v1 * scale[64 + l] + shift[64 + l]);
    float p = v0 * Wf2[l] + v1 * Wf2[64 + l];
    for (int o = 32; o > 0; o >>= 1) p += __shfl_down(p, o);
    if (l == 0) out[wid] = p + bf2[0];
}

extern "C" void kernel_launch(void* const* d_in, const int* in_sizes, int n_in, void* d_out,
                              int out_size, void* d_ws, size_t ws_size, hipStream_t stream) {
    const float* x = (const float*)d_in[0];
    const int* esrc = (const int*)d_in[1];
    const int* edst = (const int*)d_in[2];
    const float* W1 = (const float*)d_in[3];
    const float* b1 = (const float*)d_in[4];
    const float* g1 = (const float*)d_in[5];
    const float* be1 = (const float*)d_in[6];
    const float* W2 = (const float*)d_in[7];
    const float* b2 = (const float*)d_in[8];
    const float* eps_gin = (const float*)d_in[9];
    const float* g_bn = (const float*)d_in[10];
    const float* b_bn = (const float*)d_in[11];
    const float* Wf1 = (const float*)d_in[12];
    const float* bf1 = (const float*)d_in[13];
    const float* gf = (const float*)d_in[14];
    const float* bef = (const float*)d_in[15];
    const float* Wf2 = (const float*)d_in[16];
    const float* bf2 = (const float*)d_in[17];
    float* out = (float*)d_out;

    int N = in_sizes[0] / 64;
    int E = in_sizes[1];
    float invN = 1.0f / (float)N;

    float* ws = (float*)d_ws;
    size_t ND = (size_t)N * 64;
    float* X = ws;            // raw layer output (pre outer-BN)
    float* S1 = ws + ND;      // h1
    float* S2 = ws + 2 * ND;  // agg
    float* HF = S1;           // head hidden (N x 128) spans S1+S2
    float* stats = ws + 3 * ND;
    // stats sets of 512 floats: [sums 2C][scale @+256][shift @+384]
    // s0: L0 inner, s1: L0 outer, s2: L1 inner, s3: L1 outer, s4: L2 inner, s5: head
    int* ibase = (int*)(stats + 3072);
    int* cnt = ibase;
    int* ptr = ibase + N;
    int* cursor = ibase + 2 * N;
    int* blksum = ibase + 3 * N;
    int* nbr = ibase + 3 * N + 256;

    zero_kernel<<<(3072 + N + 255) / 256, 256, 0, stream>>>(stats, 3072 + N);

    int nb1 = (N + 1023) / 1024;
    hist_kernel<<<(E + 255) / 256, 256, 0, stream>>>(edst, cnt, E);
    scan1_kernel<<<nb1, 256, 0, stream>>>(cnt, ptr, blksum, N);
    scan2_kernel<<<1, 256, 0, stream>>>(blksum, nb1);
    scan3_kernel<<<(N + 255) / 256, 256, 0, stream>>>(ptr, blksum, cursor, N);
    fill_kernel<<<(E + 255) / 256, 256, 0, stream>>>(esrc, edst, cursor, nbr, E);

    int gblocks = (N * 64 + 255) / 256;
    for (int i = 0; i < 3; i++) {
        float* st = stats + (size_t)(2 * i) * 512;      // inner BN sums
        float* so = stats + (size_t)(2 * i + 1) * 512;  // outer BN sums (layers 0,1 only)
        if (i == 0) {
            gather_kernel<false><<<gblocks, 256, 0, stream>>>(x, ptr, cnt, nbr, eps_gin, i,
                                                              nullptr, nullptr, S2, N);
        } else {
            float* sp = stats + (size_t)(2 * (i - 1) + 1) * 512;  // prev outer BN
            gather_kernel<true><<<gblocks, 256, 0, stream>>>(X, ptr, cnt, nbr, eps_gin, i,
                                                             sp + 256, sp + 384, S2, N);
        }
        gemm_kernel<64><<<(N + 63) / 64, 256, 0, stream>>>(S2, W1 + (size_t)i * 4096,
                                                           b1 + (size_t)i * 64, nullptr, nullptr,
                                                           S1, st, N);
        finalize_kernel<<<1, 64, 0, stream>>>(st, g1 + (size_t)i * 64, be1 + (size_t)i * 64,
                                              st + 256, st + 384, 64, invN);
        // layer L-1 has no outer BN -> no stats accumulation (slot-5 collision fix)
        gemm_kernel<64><<<(N + 63) / 64, 256, 0, stream>>>(S1, W2 + (size_t)i * 4096,
                                                           b2 + (size_t)i * 64, st + 256,
                                                           st + 384, X, (i < 2) ? so : nullptr,
                                                           N);
        if (i < 2) {
            finalize_kernel<<<1, 64, 0, stream>>>(so, g_bn + (size_t)i * 64,
                                                  b_bn + (size_t)i * 64, so + 256, so + 384, 64,
                                                  invN);
        }
    }

    float* sf = stats + (size_t)5 * 512;
    gemm_kernel<128><<<(N + 63) / 64, 256, 0, stream>>>(X, Wf1, bf1, nullptr, nullptr, HF, sf, N);
    finalize_kernel<<<1, 128, 0, stream>>>(sf, gf, bef, sf + 256, sf + 384, 128, invN);
    head_out_kernel<<<(N + 3) / 4, 256, 0, stream>>>(HF, sf + 256, sf + 384, Wf2, bf2, out, N);
}

// Round 5
// 737.678 us; speedup vs baseline: 7.0211x; 2.0079x over previous
//
#include <hip/hip_runtime.h>

#define LRELU(x) ((x) > 0.0f ? (x) : 0.01f * (x))

__global__ void zero_kernel(float* p, int n) {
    int i = blockIdx.x * blockDim.x + threadIdx.x;
    if (i < n) p[i] = 0.0f;
}

// ---------- CSR build ----------
__global__ void hist_kernel(const int* __restrict__ dst, int* __restrict__ cnt, int E) {
    int e = blockIdx.x * blockDim.x + threadIdx.x;
    if (e < E) atomicAdd(&cnt[dst[e]], 1);
}

__global__ __launch_bounds__(256) void scan1_kernel(const int* __restrict__ cnt,
                                                    int* __restrict__ ptr,
                                                    int* __restrict__ blksum, int n) {
    __shared__ int sh[256];
    int t = threadIdx.x;
    int base = blockIdx.x * 1024 + t * 4;
    int c0 = (base + 0 < n) ? cnt[base + 0] : 0;
    int c1 = (base + 1 < n) ? cnt[base + 1] : 0;
    int c2 = (base + 2 < n) ? cnt[base + 2] : 0;
    int c3 = (base + 3 < n) ? cnt[base + 3] : 0;
    int tsum = c0 + c1 + c2 + c3;
    sh[t] = tsum;
    __syncthreads();
    for (int o = 1; o < 256; o <<= 1) {
        int v = (t >= o) ? sh[t - o] : 0;
        __syncthreads();
        sh[t] += v;
        __syncthreads();
    }
    int excl = sh[t] - tsum;
    if (base + 0 < n) ptr[base + 0] = excl;
    excl += c0;
    if (base + 1 < n) ptr[base + 1] = excl;
    excl += c1;
    if (base + 2 < n) ptr[base + 2] = excl;
    excl += c2;
    if (base + 3 < n) ptr[base + 3] = excl;
    if (t == 255) blksum[blockIdx.x] = sh[255];
}

__global__ __launch_bounds__(256) void scan2_kernel(int* __restrict__ blksum, int nb) {
    __shared__ int sh[256];
    int t = threadIdx.x;
    int v0 = (t < nb) ? blksum[t] : 0;
    sh[t] = v0;
    __syncthreads();
    for (int o = 1; o < 256; o <<= 1) {
        int v = (t >= o) ? sh[t - o] : 0;
        __syncthreads();
        sh[t] += v;
        __syncthreads();
    }
    if (t < nb) blksum[t] = sh[t] - v0;
}

__global__ void scan3_kernel(int* __restrict__ ptr, const int* __restrict__ blksum,
                             int* __restrict__ cursor, int n) {
    int i = blockIdx.x * blockDim.x + threadIdx.x;
    if (i >= n) return;
    int p = ptr[i] + blksum[i >> 10];
    ptr[i] = p;
    cursor[i] = p;
}

__global__ void fill_kernel(const int* __restrict__ src, const int* __restrict__ dst,
                            int* __restrict__ cursor, int* __restrict__ nbr, int E) {
    int e = blockIdx.x * blockDim.x + threadIdx.x;
    if (e >= E) return;
    int d = dst[e];
    int pos = atomicAdd(&cursor[d], 1);
    nbr[pos] = src[e];
}

// ---------- fp32 -> bf16 (RNE) feature table, optional BN+LeakyReLU fused ----------
// each thread: 8 floats -> 4 packed uints (16B store)
template <bool ACT>
__global__ __launch_bounds__(256) void to_bf16_kernel(const float* __restrict__ in,
                                                      const float* __restrict__ scale,
                                                      const float* __restrict__ shift,
                                                      uint* __restrict__ table, int n8) {
    int i = blockIdx.x * blockDim.x + threadIdx.x;
    if (i >= n8) return;
    float4 a = *(const float4*)&in[(size_t)i * 8];
    float4 b = *(const float4*)&in[(size_t)i * 8 + 4];
    if (ACT) {
        int d = (i * 8) & 63;
        a.x = LRELU(a.x * scale[d + 0] + shift[d + 0]);
        a.y = LRELU(a.y * scale[d + 1] + shift[d + 1]);
        a.z = LRELU(a.z * scale[d + 2] + shift[d + 2]);
        a.w = LRELU(a.w * scale[d + 3] + shift[d + 3]);
        b.x = LRELU(b.x * scale[d + 4] + shift[d + 4]);
        b.y = LRELU(b.y * scale[d + 5] + shift[d + 5]);
        b.z = LRELU(b.z * scale[d + 6] + shift[d + 6]);
        b.w = LRELU(b.w * scale[d + 7] + shift[d + 7]);
    }
    float v[8] = {a.x, a.y, a.z, a.w, b.x, b.y, b.z, b.w};
    uint p[4];
#pragma unroll
    for (int j = 0; j < 4; j++) {
        uint lo = __float_as_uint(v[2 * j + 0]);
        uint hi = __float_as_uint(v[2 * j + 1]);
        lo = (lo + 0x7fffu + ((lo >> 16) & 1u)) >> 16;  // RNE
        hi = (hi + 0x7fffu + ((hi >> 16) & 1u)) & 0xffff0000u;
        p[j] = lo | hi;
    }
    *(uint4*)&table[(size_t)i * 4] = make_uint4(p[0], p[1], p[2], p[3]);
}

// ---------- aggregation: one wave per node; half-waves split the neighbor list;
// lane holds features (2*sl, 2*sl+1) via one uint (2 bf16); fp32 accumulate ----------
__global__ __launch_bounds__(256) void gather_kernel(const ushort* __restrict__ table,
                                                     const int* __restrict__ ptr,
                                                     const int* __restrict__ cnt,
                                                     const int* __restrict__ nbr,
                                                     const float* __restrict__ eps_gin, int layer,
                                                     float* __restrict__ agg, int N) {
    int gtid = blockIdx.x * blockDim.x + threadIdx.x;
    int node = gtid >> 6;
    if (node >= N) return;
    int lane = threadIdx.x & 63;
    int half = lane >> 5;
    int sl = lane & 31;
    int start = ptr[node];
    int deg = cnt[node];
    float a0 = 0.0f, a1 = 0.0f;
    int j = half;
    for (; j + 2 < deg; j += 4) {
        int nA = nbr[start + j];
        int nB = nbr[start + j + 2];
        uint vA = *(const uint*)(table + (size_t)nA * 64 + sl * 2);
        uint vB = *(const uint*)(table + (size_t)nB * 64 + sl * 2);
        a0 += __uint_as_float(vA << 16) + __uint_as_float(vB << 16);
        a1 += __uint_as_float(vA & 0xffff0000u) + __uint_as_float(vB & 0xffff0000u);
    }
    for (; j < deg; j += 2) {
        int nA = nbr[start + j];
        uint vA = *(const uint*)(table + (size_t)nA * 64 + sl * 2);
        a0 += __uint_as_float(vA << 16);
        a1 += __uint_as_float(vA & 0xffff0000u);
    }
    // combine halves
    a0 += __shfl(a0, lane ^ 32);
    a1 += __shfl(a1, lane ^ 32);
    // self term
    uint vs = *(const uint*)(table + (size_t)node * 64 + sl * 2);
    float ep = 1.0f + eps_gin[layer];
    a0 += ep * __uint_as_float(vs << 16);
    a1 += ep * __uint_as_float(vs & 0xffff0000u);
    if (half == 0) *(float2*)&agg[(size_t)node * 64 + sl * 2] = make_float2(a0, a1);
}

__global__ void finalize_kernel(const float* __restrict__ sums, const float* __restrict__ g,
                                const float* __restrict__ be, float* __restrict__ scale,
                                float* __restrict__ shift, int C, float invN) {
    int d = threadIdx.x;
    if (d >= C) return;
    float mean = sums[d] * invN;
    float var = sums[C + d] * invN - mean * mean;
    float sc = g[d] * rsqrtf(var + 1e-5f);
    scale[d] = sc;
    shift[d] = be[d] - mean * sc;
}

// out[nrows x COLS] = act(in[nrows x 64]) @ W[64 x COLS] + bias
// optional fused col-stats (sums != nullptr)
// launch_bounds(256,4): cap VGPR<=128 -> 4 waves/SIMD (r4: 256 VGPR -> 10% occ, 3.5% VALUBusy)
template <int COLS>
__global__ __launch_bounds__(256, 4) void gemm_kernel(const float* __restrict__ in,
                                                      const float* __restrict__ W,
                                                      const float* __restrict__ bias,
                                                      const float* __restrict__ scale,
                                                      const float* __restrict__ shift,
                                                      float* __restrict__ out,
                                                      float* __restrict__ sums, int nrows) {
    __shared__ float inT[64][68];   // [k][row], rows 16B-aligned
    __shared__ float ws[64][COLS];  // [k][col]
    int t = threadIdx.x;
    int row0 = blockIdx.x * 64;

    for (int i = 0; i < 4; i++) {
        int f = t + 256 * i;
        int r = f >> 4;
        int ch = f & 15;
        int gr = row0 + r;
        float4 v = make_float4(0.f, 0.f, 0.f, 0.f);
        if (gr < nrows) v = *(const float4*)&in[(size_t)gr * 64 + ch * 4];
        if (scale) {
            int d = ch * 4;
            v.x = LRELU(v.x * scale[d + 0] + shift[d + 0]);
            v.y = LRELU(v.y * scale[d + 1] + shift[d + 1]);
            v.z = LRELU(v.z * scale[d + 2] + shift[d + 2]);
            v.w = LRELU(v.w * scale[d + 3] + shift[d + 3]);
        }
        inT[ch * 4 + 0][r] = v.x;
        inT[ch * 4 + 1][r] = v.y;
        inT[ch * 4 + 2][r] = v.z;
        inT[ch * 4 + 3][r] = v.w;
    }
    for (int i = 0; i < COLS / 16; i++) {
        int f = t + 256 * i;
        int k = f / (COLS / 4);
        int c4 = f % (COLS / 4);
        *(float4*)&ws[k][c4 * 4] = *(const float4*)&W[(size_t)k * COLS + c4 * 4];
    }
    __syncthreads();

    constexpr int NCH = COLS / 64;
    int rg = t >> 4;
    int cg = t & 15;
    int r0 = rg * 4;
    int c0 = cg * 4;
    float acc[4][NCH * 4];
#pragma unroll
    for (int r = 0; r < 4; r++)
#pragma unroll
        for (int c = 0; c < NCH * 4; c++) acc[r][c] = 0.0f;

#pragma unroll 16
    for (int k = 0; k < 64; k++) {
        float4 a = *(const float4*)&inT[k][r0];
        float ar[4] = {a.x, a.y, a.z, a.w};
#pragma unroll
        for (int jj = 0; jj < NCH; jj++) {
            float4 w4 = *(const float4*)&ws[k][c0 + jj * 64];
            float wr[4] = {w4.x, w4.y, w4.z, w4.w};
#pragma unroll
            for (int r = 0; r < 4; r++)
#pragma unroll
                for (int c = 0; c < 4; c++) acc[r][jj * 4 + c] += ar[r] * wr[c];
        }
    }

    float ps[NCH * 4], ps2[NCH * 4];
#pragma unroll
    for (int c = 0; c < NCH * 4; c++) ps[c] = ps2[c] = 0.0f;
#pragma unroll
    for (int r = 0; r < 4; r++) {
        int gr = row0 + r0 + r;
        if (gr < nrows) {
#pragma unroll
            for (int jj = 0; jj < NCH; jj++) {
                float4 bv = *(const float4*)&bias[c0 + jj * 64];
                float4 o = make_float4(acc[r][jj * 4 + 0] + bv.x, acc[r][jj * 4 + 1] + bv.y,
                                       acc[r][jj * 4 + 2] + bv.z, acc[r][jj * 4 + 3] + bv.w);
                *(float4*)&out[(size_t)gr * COLS + c0 + jj * 64] = o;
                ps[jj * 4 + 0] += o.x;
                ps2[jj * 4 + 0] += o.x * o.x;
                ps[jj * 4 + 1] += o.y;
                ps2[jj * 4 + 1] += o.y * o.y;
                ps[jj * 4 + 2] += o.z;
                ps2[jj * 4 + 2] += o.z * o.z;
                ps[jj * 4 + 3] += o.w;
                ps2[jj * 4 + 3] += o.w * o.w;
            }
        }
    }

    if (sums == nullptr) return;  // layer L-1 outer output: no BN stats

    __syncthreads();
    float* red = &inT[0][0];
    float* red2 = red + 16 * COLS;
#pragma unroll
    for (int jj = 0; jj < NCH; jj++) {
        *(float4*)&red[rg * COLS + c0 + jj * 64] = *(float4*)&ps[jj * 4];
        *(float4*)&red2[rg * COLS + c0 + jj * 64] = *(float4*)&ps2[jj * 4];
    }
    __syncthreads();
    if (t < COLS) {
        float s = 0.0f, s2 = 0.0f;
#pragma unroll
        for (int j = 0; j < 16; j++) {
            s += red[j * COLS + t];
            s2 += red2[j * COLS + t];
        }
        atomicAdd(&sums[t], s);
        atomicAdd(&sums[COLS + t], s2);
    }
}

__global__ void head_out_kernel(const float* __restrict__ hf, const float* __restrict__ scale,
                                const float* __restrict__ shift, const float* __restrict__ Wf2,
                                const float* __restrict__ bf2, float* __restrict__ out,
                                int nrows) {
    int gtid = blockIdx.x * blockDim.x + threadIdx.x;
    int wid = gtid >> 6;
    int l = threadIdx.x & 63;
    if (wid >= nrows) return;
    float v0 = hf[(size_t)wid * 128 + l];
    float v1 = hf[(size_t)wid * 128 + 64 + l];
    v0 = LRELU(v0 * scale[l] + shift[l]);
    v1 = LRELU(v1 * scale[64 + l] + shift[64 + l]);
    float p = v0 * Wf2[l] + v1 * Wf2[64 + l];
    for (int o = 32; o > 0; o >>= 1) p += __shfl_down(p, o);
    if (l == 0) out[wid] = p + bf2[0];
}

extern "C" void kernel_launch(void* const* d_in, const int* in_sizes, int n_in, void* d_out,
                              int out_size, void* d_ws, size_t ws_size, hipStream_t stream) {
    const float* x = (const float*)d_in[0];
    const int* esrc = (const int*)d_in[1];
    const int* edst = (const int*)d_in[2];
    const float* W1 = (const float*)d_in[3];
    const float* b1 = (const float*)d_in[4];
    const float* g1 = (const float*)d_in[5];
    const float* be1 = (const float*)d_in[6];
    const float* W2 = (const float*)d_in[7];
    const float* b2 = (const float*)d_in[8];
    const float* eps_gin = (const float*)d_in[9];
    const float* g_bn = (const float*)d_in[10];
    const float* b_bn = (const float*)d_in[11];
    const float* Wf1 = (const float*)d_in[12];
    const float* bf1 = (const float*)d_in[13];
    const float* gf = (const float*)d_in[14];
    const float* bef = (const float*)d_in[15];
    const float* Wf2 = (const float*)d_in[16];
    const float* bf2 = (const float*)d_in[17];
    float* out = (float*)d_out;

    int N = in_sizes[0] / 64;
    int E = in_sizes[1];
    float invN = 1.0f / (float)N;

    float* ws = (float*)d_ws;
    size_t ND = (size_t)N * 64;
    float* X = ws;            // raw layer output (pre outer-BN)
    float* S1 = ws + ND;      // bf16 table (first half, dead by gemm1) then h1
    float* S2 = ws + 2 * ND;  // agg
    float* HF = S1;           // head hidden (N x 128) spans S1+S2
    uint* table = (uint*)S1;  // bf16 xact table: N*64 ushorts = N*32 uints (12.8 MB)
    float* stats = ws + 3 * ND;
    // stats sets of 512 floats: [sums 2C][scale @+256][shift @+384]
    int* ibase = (int*)(stats + 3072);
    int* cnt = ibase;
    int* ptr = ibase + N;
    int* cursor = ibase + 2 * N;
    int* blksum = ibase + 3 * N;
    int* nbr = ibase + 3 * N + 256;

    zero_kernel<<<(3072 + N + 255) / 256, 256, 0, stream>>>(stats, 3072 + N);

    int nb1 = (N + 1023) / 1024;
    hist_kernel<<<(E + 255) / 256, 256, 0, stream>>>(edst, cnt, E);
    scan1_kernel<<<nb1, 256, 0, stream>>>(cnt, ptr, blksum, N);
    scan2_kernel<<<1, 256, 0, stream>>>(blksum, nb1);
    scan3_kernel<<<(N + 255) / 256, 256, 0, stream>>>(ptr, blksum, cursor, N);
    fill_kernel<<<(E + 255) / 256, 256, 0, stream>>>(esrc, edst, cursor, nbr, E);

    int n8 = N * 8;  // threads for to_bf16 (8 floats each)
    int gblocks = (N * 64 + 255) / 256;
    for (int i = 0; i < 3; i++) {
        float* st = stats + (size_t)(2 * i) * 512;      // inner BN sums
        float* so = stats + (size_t)(2 * i + 1) * 512;  // outer BN sums (layers 0,1)
        if (i == 0) {
            to_bf16_kernel<false><<<(n8 + 255) / 256, 256, 0, stream>>>(x, nullptr, nullptr,
                                                                        table, n8);
        } else {
            float* sp = stats + (size_t)(2 * (i - 1) + 1) * 512;  // prev outer BN
            to_bf16_kernel<true><<<(n8 + 255) / 256, 256, 0, stream>>>(X, sp + 256, sp + 384,
                                                                       table, n8);
        }
        gather_kernel<<<gblocks, 256, 0, stream>>>((const ushort*)table, ptr, cnt, nbr, eps_gin,
                                                   i, S2, N);
        gemm_kernel<64><<<(N + 63) / 64, 256, 0, stream>>>(S2, W1 + (size_t)i * 4096,
                                                           b1 + (size_t)i * 64, nullptr, nullptr,
                                                           S1, st, N);
        finalize_kernel<<<1, 64, 0, stream>>>(st, g1 + (size_t)i * 64, be1 + (size_t)i * 64,
                                              st + 256, st + 384, 64, invN);
        gemm_kernel<64><<<(N + 63) / 64, 256, 0, stream>>>(S1, W2 + (size_t)i * 4096,
                                                           b2 + (size_t)i * 64, st + 256,
                                                           st + 384, X, (i < 2) ? so : nullptr,
                                                           N);
        if (i < 2) {
            finalize_kernel<<<1, 64, 0, stream>>>(so, g_bn + (size_t)i * 64,
                                                  b_bn + (size_t)i * 64, so + 256, so + 384, 64,
                                                  invN);
        }
    }

    float* sf = stats + (size_t)5 * 512;
    gemm_kernel<128><<<(N + 63) / 64, 256, 0, stream>>>(X, Wf1, bf1, nullptr, nullptr, HF, sf, N);
    finalize_kernel<<<1, 128, 0, stream>>>(sf, gf, bef, sf + 256, sf + 384, 128, invN);
    head_out_kernel<<<(N + 3) / 4, 256, 0, stream>>>(HF, sf + 256, sf + 384, Wf2, bf2, out, N);
}